// Round 8
// baseline (293.725 us; speedup 1.0000x reference)
//
#include <hip/hip_runtime.h>
#include <math.h>

// DSSIM (mean), B=32 C=3 H=W=512 fp32, separable 11x11 Gaussian.
// R12 = R11 math (field-packed v2f FMA, 4 fields {A,B,S,X}, SLOT=32 +
// rotation) restructured as a HALF-CHUNK pipeline to fix occupancy:
//  - R11 post-mortem: L3-warm replays run at identical 129us with ZERO
//    HBM traffic -> not memory-bound. Pipe floors: VALU ~31-45us, LDS
//    ~25us; wall 129us at 33% occupancy -> latency-bound, LDS/wave is
//    the binding resource (37.9KB ring -> 4 blocks/CU).
//  - h/v alternate at 32-row half-chunks: live window = 32+10 = 42 ring
//    rows -> LDS 21.5KB -> 7 blocks/CU (28 waves, 87% theoretical).
//  - h-tasks shrink to 4-col subtasks so steady phases stay at exactly
//    256 tasks (8 subtasks/row x 32 rows); 16-float window, float4-
//    aligned; per-col FMA count unchanged (44 col-taps -> 88 pk-FMA).
//  - v-phase: 4 rows/thread per half-chunk (8 yg x 4 = 32), reads 14
//    ring rows; mab/msx shrink to 4 pairs (16 VGPR).
//  - barriers 2x (8/block) - affordable with 7 resident blocks.
//  - ring safety: h(hc+1) writes slots of rows <= 32hc-6; v(hc+1) needs
//    rows >= 32hc+27 -> disjoint.
//  - launch bounds (256,4) = VGPR cap 128 only (does NOT limit blocks/CU);
//    (256,5+) risks the R5/R6 catastrophic-spill mode.
//  - NO lambdas/helpers (R3: un-inlined helpers demote arrays to scratch).

namespace {
constexpr int IMG = 512;
constexpr int TW = 32;                 // strip width
constexpr int HC = 32;                 // rows per half-chunk
constexpr int RING = HC + 10;          // 42 ring rows
constexpr int SLOT = 32;               // floats per (xg, ringrow) slot
constexpr int XGN = TW / 8;            // 4 col-groups
constexpr int SEGR = 128;              // rows per block segment
constexpr int NHC = SEGR / HC;         // 4 half-chunks per segment
constexpr int SEGN = IMG / SEGR;       // 4 segments per strip
constexpr int CTILES = IMG / TW;       // 16 strips per image
constexpr int NIMG = 96;               // 32*3
constexpr float C1c = 1e-4f;
constexpr float C2c = 9e-4f;
constexpr float INV_N = 1.0f / 25165824.0f;  // 1/(96*512*512)
}

typedef float v2f __attribute__((ext_vector_type(2)));

__global__ void dssim_zero(float* ws) { ws[0] = 0.0f; }

__global__ void dssim_final(const float* __restrict__ ws, float* __restrict__ out) {
  out[0] = ws[0] * INV_N;
}

// accumulate one window elem (E = window_idx - 3, compile-time const) into
// the 4 column accumulators. d01={a,b}, d23={a2+b2, ab}; weight splat w2[t].
#define ACC_E(E, VA, VB) do {                                              \
    const int e_ = (E);                                                    \
    if (e_ >= 0 && e_ < 14) {                                              \
      float va_ = (VA), vb_ = (VB);                                        \
      float pab_ = va_ * vb_;                                              \
      float ps_  = __builtin_fmaf(vb_, vb_, va_ * va_);                    \
      v2f d01_; d01_.x = va_; d01_.y = vb_;                                \
      v2f d23_; d23_.x = ps_; d23_.y = pab_;                               \
      _Pragma("unroll")                                                    \
      for (int j_ = 0; j_ < 4; ++j_) {                                     \
        const int t_ = e_ - j_;                                            \
        if (t_ >= 0 && t_ < 11) {                                          \
          oab[j_] = __builtin_elementwise_fma(w2[t_], d01_, oab[j_]);      \
          osx[j_] = __builtin_elementwise_fma(w2[t_], d23_, osx[j_]);      \
        }                                                                  \
      }                                                                    \
    }                                                                      \
  } while (0)

__global__ __launch_bounds__(256, 4) void dssim_main(
    const float* __restrict__ im1, const float* __restrict__ im2,
    const float* __restrict__ gk, float* __restrict__ ws)
{
  __shared__ float sR[XGN * RING * SLOT];   // 21,504 B -> 7 blocks/CU

  const int tid = threadIdx.x;
  const int bid = blockIdx.x;
  const int img = bid >> 6;          // 64 blocks per image (16 strips x 4 segs)
  const int rem = bid & 63;
  const int tsx = rem & 15;
  const int seg = rem >> 4;
  const int X0s = tsx * TW;
  const int Y0  = seg * SEGR;

  const float* __restrict__ p1 = im1 + (size_t)img * (IMG * IMG);
  const float* __restrict__ p2 = im2 + (size_t)img * (IMG * IMG);

  // k1[i] = k2d[i][5] / sqrt(k2d[5][5])  (separable, sum(k1)=1)
  // weight SPLATS: w2[t].x == w2[t].y == wt[t]
  v2f w2[11];
  {
    float ic = 1.0f / sqrtf(gk[5 * 11 + 5]);
    #pragma unroll
    for (int t = 0; t < 11; ++t) {
      float w = gk[t * 11 + 5] * ic;
      w2[t].x = w; w2[t].y = w;
    }
  }

  // v-phase mapping: one column per thread, 4 rows per half-chunk
  const int c   = tid & 31;
  const int yg  = tid >> 5;          // 0..7
  const int xg3 = c >> 3;
  const int cl  = c & 7;

  float lsum = 0.f;

  for (int hc = 0; hc < NHC; ++hc) {
    // ---- h-phase: produce new h-rows into the ring (4-col subtasks) ----
    // hc==0: rows -5..36 (42 rows, 336 tasks); hc>=1: 32 rows, 256 tasks.
    const int r0    = (hc == 0) ? -5 : HC * hc + 5;        // local row
    const int ntask = (hc == 0) ? 8 * RING : 8 * HC;       // 336 / 256
    for (int t = tid; t < ntask; t += 256) {
      const int cs = t & 7;                  // col-subtask 0..7
      const int dr = t >> 3;
      const int rl = r0 + dr;                // local row in [-5, SEGR+4]
      const int ry = Y0 + rl;                // global row
      const int slot = (rl + 5) % RING;      // ring slot row
      const int xg = cs >> 1;
      const int cb = X0s + 4 * cs - 8;       // window base col, 4-aligned

      // col-j accumulators (4 cols): oab[j]={A,B}, osx[j]={S,X}
      v2f oab[4], osx[4];
      #pragma unroll
      for (int j = 0; j < 4; ++j) { oab[j] = 0.f; osx[j] = 0.f; }

      if ((unsigned)ry < (unsigned)IMG) {
        const float* row1 = p1 + (size_t)ry * IMG;
        const float* row2 = p2 + (size_t)ry * IMG;
        if (cb >= 0 && cb + 16 <= IMG) {
          // interior: 4 float4 pairs; window elems i=3..16 -> e = i-3
          #pragma unroll
          for (int g = 0; g < 4; ++g) {
            float4 v1 = *(const float4*)(row1 + cb + 4 * g);
            float4 v2 = *(const float4*)(row2 + cb + 4 * g);
            ACC_E(4 * g - 3, v1.x, v2.x);
            ACC_E(4 * g - 2, v1.y, v2.y);
            ACC_E(4 * g - 1, v1.z, v2.z);
            ACC_E(4 * g + 0, v1.w, v2.w);
          }
        } else {
          // boundary: scalar guarded loads (window idx 3..16)
          #pragma unroll
          for (int i = 3; i <= 16; ++i) {
            int cc = cb + i;
            float va = 0.f, vb = 0.f;
            if ((unsigned)cc < (unsigned)IMG) { va = row1[cc]; vb = row2[cc]; }
            ACC_E(i - 3, va, vb);
          }
        }
      }

      // store: strip-col = 4*cs + j; xg = cs>>1; col-in-group = 4*(cs&1)+j
      const int base = (xg * RING + slot) * SLOT;
      const int rot  = 4 * (slot & 7) + 8 * xg;
      const int c0   = 4 * (cs & 1);
      #pragma unroll
      for (int j = 0; j < 4; ++j) {
        const int a = base + ((4 * (c0 + j) + rot) & 31);
        *(v2f*)&sR[a]     = oab[j];
        *(v2f*)&sR[a + 2] = osx[j];
      }
    }
    __syncthreads();

    // ---- v-phase: 4 output rows per thread + SSIM ----
    v2f mab[4], msx[4];
    #pragma unroll
    for (int j = 0; j < 4; ++j) { mab[j] = 0.f; msx[j] = 0.f; }

    const int y0 = HC * hc + yg * 4;           // local first output row
    int idx = y0 % RING;                       // ring slot of h-row (y0-5)
    #pragma unroll
    for (int rr = 0; rr < 14; ++rr) {
      const int a = (xg3 * RING + idx) * SLOT +
                    ((4 * cl + 4 * (idx & 7) + 8 * xg3) & 31);
      float4 v4 = *(const float4*)&sR[a];
      v2f d01; d01.x = v4.x; d01.y = v4.y;     // {A,B}
      v2f d23; d23.x = v4.z; d23.y = v4.w;     // {S,X}
      #pragma unroll
      for (int j = 0; j < 4; ++j) {
        const int t = rr - j;
        if (t >= 0 && t < 11) {
          mab[j] = __builtin_elementwise_fma(w2[t], d01, mab[j]);
          msx[j] = __builtin_elementwise_fma(w2[t], d23, msx[j]);
        }
      }
      idx++; if (idx == RING) idx = 0;
    }

    #pragma unroll
    for (int j = 0; j < 4; ++j) {
      float m1 = mab[j].x, m2 = mab[j].y;
      float eS = msx[j].x, eX = msx[j].y;
      float m1s = m1 * m1, m2s = m2 * m2, m12 = m1 * m2;
      float sS  = eS - m1s - m2s;              // s11 + s22
      float s12 = eX - m12;
      float num = (2.f * m12 + C1c) * (2.f * s12 + C2c);
      float den = (m1s + m2s + C1c) * (sS + C2c);
      lsum += (1.f - num * __builtin_amdgcn_rcpf(den)) * 0.5f;
    }
    __syncthreads();
  }

  // wave reduce -> block reduce -> ONE atomic per block (6144 total)
  #pragma unroll
  for (int off = 32; off > 0; off >>= 1) lsum += __shfl_down(lsum, off);
  if ((tid & 63) == 0) sR[tid >> 6] = lsum;
  __syncthreads();
  if (tid == 0) atomicAdd(ws, sR[0] + sR[1] + sR[2] + sR[3]);
}

extern "C" void kernel_launch(void* const* d_in, const int* in_sizes, int n_in,
                              void* d_out, int out_size, void* d_ws, size_t ws_size,
                              hipStream_t stream) {
  const float* im1 = (const float*)d_in[0];
  const float* im2 = (const float*)d_in[1];
  const float* gk  = (const float*)d_in[2];
  float* out = (float*)d_out;
  float* ws  = (float*)d_ws;

  hipLaunchKernelGGL(dssim_zero, dim3(1), dim3(1), 0, stream, ws);
  hipLaunchKernelGGL(dssim_main, dim3(NIMG * CTILES * SEGN), dim3(256), 0, stream,
                     im1, im2, gk, ws);
  hipLaunchKernelGGL(dssim_final, dim3(1), dim3(1), 0, stream, ws, out);
}

// Round 9
// 275.870 us; speedup vs baseline: 1.0647x; 1.0647x over previous
//
#include <hip/hip_runtime.h>
#include <math.h>

// DSSIM (mean), B=32 C=3 H=W=512 fp32, separable 11x11 Gaussian.
// R13 = R11 structure EXACTLY (RB=64 ring, RING=74, SLOT=32+rotation,
// 8-col h-tasks, field-packed v2f math, absmax=0.0) + two changes:
//  1) inline-asm v_pk_fma_f32 for every packed FMA. R11 post-mortem:
//     measured VALU-busy (79us) is 2.8x the static instruction count
//     (28us) -- consistent with the compiler SCALARIZING the v2f
//     __builtin_elementwise_fma. Inline asm makes packing certain.
//     Plain (non-volatile, no memory clobber) asm stays schedulable.
//  2) SEGR 128 -> 256 (SEGN=2, grid 3072, 12 blocks/CU): prefill
//     imbalance (296 tasks vs 256 threads = +1 task-time) amortizes over
//     4 chunks not 2; segment halo rows halve. Ring safety re-derived
//     for NCHUNK=4: h(kc) overwrites slots of rows <= 64kc-6 only; v(kc)
//     needs rows >= 64kc-5 -> disjoint.
//  - R12 lesson: occupancy metric is barrier-time-average, NOT LDS-bound;
//    halving LDS did not raise it (30%) and perf+accuracy regressed.
//    Reverted that structure entirely.
//  - launch bounds (256,4): (256,5) = catastrophic spill (R5/R6).
//  - NO lambdas/helpers (R3: un-inlined helpers demote arrays to scratch).

namespace {
constexpr int IMG = 512;
constexpr int TW = 32;                 // strip width
constexpr int RB = 64;                 // output rows per chunk
constexpr int RING = RB + 10;          // 74 ring rows
constexpr int SLOT = 32;               // floats per (xg, ringrow) slot
constexpr int XGN = TW / 8;            // 4 col-groups
constexpr int SEGR = 256;              // rows per block segment
constexpr int NCHUNK = SEGR / RB;      // 4 chunks per segment
constexpr int SEGN = IMG / SEGR;       // 2 segments per strip
constexpr int CTILES = IMG / TW;       // 16 strips per image
constexpr int NIMG = 96;               // 32*3
constexpr float C1c = 1e-4f;
constexpr float C2c = 9e-4f;
constexpr float INV_N = 1.0f / 25165824.0f;  // 1/(96*512*512)
}

typedef float v2f __attribute__((ext_vector_type(2)));

// certain packed FMA: acc = w*d + acc (lo,hi lanes independently)
#define PKFMA(ACC, W, D)                                                   \
  asm("v_pk_fma_f32 %0, %1, %2, %0" : "+v"(ACC) : "v"(W), "v"(D))

__global__ void dssim_zero(float* ws) { ws[0] = 0.0f; }

__global__ void dssim_final(const float* __restrict__ ws, float* __restrict__ out) {
  out[0] = ws[0] * INV_N;
}

// accumulate one window elem (E = window_idx - 3, compile-time const) into
// the 8 column accumulators. d01={a,b}, d23={a2+b2, ab}; weight splat w2[t].
#define ACC_E(E, VA, VB) do {                                              \
    const int e_ = (E);                                                    \
    if (e_ >= 0 && e_ < 18) {                                              \
      float va_ = (VA), vb_ = (VB);                                        \
      float pab_ = va_ * vb_;                                              \
      float ps_  = __builtin_fmaf(vb_, vb_, va_ * va_);                    \
      v2f d01_; d01_.x = va_; d01_.y = vb_;                                \
      v2f d23_; d23_.x = ps_; d23_.y = pab_;                               \
      _Pragma("unroll")                                                    \
      for (int j_ = 0; j_ < 8; ++j_) {                                     \
        const int t_ = e_ - j_;                                            \
        if (t_ >= 0 && t_ < 11) {                                          \
          PKFMA(oab[j_], w2[t_], d01_);                                    \
          PKFMA(osx[j_], w2[t_], d23_);                                    \
        }                                                                  \
      }                                                                    \
    }                                                                      \
  } while (0)

__global__ __launch_bounds__(256, 4) void dssim_main(
    const float* __restrict__ im1, const float* __restrict__ im2,
    const float* __restrict__ gk, float* __restrict__ ws)
{
  __shared__ float sR[XGN * RING * SLOT];   // 37,888 B -> 4 blocks/CU

  const int tid = threadIdx.x;
  const int bid = blockIdx.x;
  const int img = bid >> 5;          // 32 blocks per image (16 strips x 2 segs)
  const int rem = bid & 31;
  const int tsx = rem & 15;
  const int seg = rem >> 4;
  const int X0s = tsx * TW;
  const int Y0  = seg * SEGR;

  const float* __restrict__ p1 = im1 + (size_t)img * (IMG * IMG);
  const float* __restrict__ p2 = im2 + (size_t)img * (IMG * IMG);

  // k1[i] = k2d[i][5] / sqrt(k2d[5][5])  (separable, sum(k1)=1)
  // weight SPLATS: w2[t].x == w2[t].y == wt[t]
  v2f w2[11];
  {
    float ic = 1.0f / sqrtf(gk[5 * 11 + 5]);
    #pragma unroll
    for (int t = 0; t < 11; ++t) {
      float w = gk[t * 11 + 5] * ic;
      w2[t].x = w; w2[t].y = w;
    }
  }

  // v-phase mapping: one column per thread, 8 rows per chunk
  const int c   = tid & 31;
  const int yg  = tid >> 5;          // 0..7
  const int xg3 = c >> 3;
  const int cl  = c & 7;

  float lsum = 0.f;

  for (int kc = 0; kc < NCHUNK; ++kc) {
    // ---- h-phase: produce new h-rows into the ring (coarse 8-col tasks) --
    const int r0    = (kc == 0) ? -5 : RB * kc + 5;        // local row
    const int ntask = (kc == 0) ? XGN * RING : XGN * RB;   // 296 / 256
    for (int t = tid; t < ntask; t += 256) {
      const int xg = t & 3, dr = t >> 2;
      const int rl = r0 + dr;                  // local row in [-5, SEGR+4]
      const int ry = Y0 + rl;                  // global row
      const int rr = (rl + 5) % RING;          // ring slot row
      const int cb = X0s + xg * 8 - 8;

      // col-j accumulators: oab[j]={A,B}, osx[j]={S,X}
      v2f oab[8], osx[8];
      #pragma unroll
      for (int j = 0; j < 8; ++j) { oab[j] = 0.f; osx[j] = 0.f; }

      if ((unsigned)ry < (unsigned)IMG) {
        const float* row1 = p1 + (size_t)ry * IMG;
        const float* row2 = p2 + (size_t)ry * IMG;
        if (cb >= 0 && cb + 24 <= IMG) {
          // interior: load one float4 pair per group, accumulate, move on
          #pragma unroll
          for (int g = 0; g < 6; ++g) {
            float4 v1 = *(const float4*)(row1 + cb + 4 * g);
            float4 v2 = *(const float4*)(row2 + cb + 4 * g);
            ACC_E(4 * g - 3, v1.x, v2.x);
            ACC_E(4 * g - 2, v1.y, v2.y);
            ACC_E(4 * g - 1, v1.z, v2.z);
            ACC_E(4 * g + 0, v1.w, v2.w);
          }
        } else {
          // boundary: scalar guarded loads (only window idx 3..20 matter)
          #pragma unroll
          for (int i = 3; i <= 20; ++i) {
            int cc = cb + i;
            float va = 0.f, vb = 0.f;
            if ((unsigned)cc < (unsigned)IMG) { va = row1[cc]; vb = row2[cc]; }
            ACC_E(i - 3, va, vb);
          }
        }
      }

      // store: col j -> {A,B} then {S,X} as two b64 at rotated quad offset
      const int base = (xg * RING + rr) * SLOT;
      const int rot  = 4 * (rr & 7) + 8 * xg;
      #pragma unroll
      for (int j = 0; j < 8; ++j) {
        const int a = base + ((4 * j + rot) & 31);
        *(v2f*)&sR[a]     = oab[j];
        *(v2f*)&sR[a + 2] = osx[j];
      }
    }
    __syncthreads();

    // ---- v-phase: 8 output rows per thread + SSIM ----
    v2f mab[8], msx[8];
    #pragma unroll
    for (int j = 0; j < 8; ++j) { mab[j] = 0.f; msx[j] = 0.f; }

    const int y0l = RB * kc + yg * 8;          // local first output row
    int idx = y0l % RING;
    #pragma unroll
    for (int rr = 0; rr < 18; ++rr) {
      const int a = (xg3 * RING + idx) * SLOT +
                    ((4 * cl + 4 * (idx & 7) + 8 * xg3) & 31);
      float4 v4 = *(const float4*)&sR[a];
      v2f d01; d01.x = v4.x; d01.y = v4.y;     // {A,B} - adjacent in v4
      v2f d23; d23.x = v4.z; d23.y = v4.w;     // {S,X} - adjacent in v4
      #pragma unroll
      for (int j = 0; j < 8; ++j) {
        const int t = rr - j;
        if (t >= 0 && t < 11) {
          PKFMA(mab[j], w2[t], d01);
          PKFMA(msx[j], w2[t], d23);
        }
      }
      idx++; if (idx == RING) idx = 0;
    }

    #pragma unroll
    for (int j = 0; j < 8; ++j) {
      float m1 = mab[j].x, m2 = mab[j].y;
      float eS = msx[j].x, eX = msx[j].y;
      float m1s = m1 * m1, m2s = m2 * m2, m12 = m1 * m2;
      float sS  = eS - m1s - m2s;              // s11 + s22
      float s12 = eX - m12;
      float num = (2.f * m12 + C1c) * (2.f * s12 + C2c);
      float den = (m1s + m2s + C1c) * (sS + C2c);
      lsum += (1.f - num * __builtin_amdgcn_rcpf(den)) * 0.5f;
    }
    __syncthreads();
  }

  // wave reduce -> block reduce -> ONE atomic per block (3072 total)
  #pragma unroll
  for (int off = 32; off > 0; off >>= 1) lsum += __shfl_down(lsum, off);
  if ((tid & 63) == 0) sR[tid >> 6] = lsum;
  __syncthreads();
  if (tid == 0) atomicAdd(ws, sR[0] + sR[1] + sR[2] + sR[3]);
}

extern "C" void kernel_launch(void* const* d_in, const int* in_sizes, int n_in,
                              void* d_out, int out_size, void* d_ws, size_t ws_size,
                              hipStream_t stream) {
  const float* im1 = (const float*)d_in[0];
  const float* im2 = (const float*)d_in[1];
  const float* gk  = (const float*)d_in[2];
  float* out = (float*)d_out;
  float* ws  = (float*)d_ws;

  hipLaunchKernelGGL(dssim_zero, dim3(1), dim3(1), 0, stream, ws);
  hipLaunchKernelGGL(dssim_main, dim3(NIMG * CTILES * SEGN), dim3(256), 0, stream,
                     im1, im2, gk, ws);
  hipLaunchKernelGGL(dssim_final, dim3(1), dim3(1), 0, stream, ws, out);
}